// Round 14
// baseline (36.192 us; speedup 1.0000x reference)
//
#include <hip/hip_runtime.h>
#include <hip/hip_fp16.h>
#include <math.h>

#define THREADS 512
#define MHALF 8192      // complex FFT length (N/2)
#define NREAL 16384
#define MIN_IDX 364     // argmin |f - 40/60|, exact fp32 (f[k]=k*15/8192 is exact)
#define MAX_IDX 2276    // argmin |f - 250/60|, exact fp32

__device__ __forceinline__ int br13(int x) {
    return (int)(__brev((unsigned)x) >> 19);
}

// Element p (a half2 = one complex) lives at cf[PHI(p)], 4-byte granularity.
// PHI(p) = p ^ ((p>>5)&31) ^ ((p>>10)&3). Measured (r8/r9):
// SQ_LDS_BANK_CONFLICT 1.29e6 (10x below the old bit0-preserving swizzle).
// PHI(p^1) = PHI(p)^1 (bit0 of p doesn't feed the masks), so a natural pair
// {even a, a+1} occupies an aligned slot pair {s&~1, s|1}, possibly swapped.
__device__ __forceinline__ int PHI(int p) {
    return p ^ ((p >> 5) & 31) ^ ((p >> 10) & 3);
}

// exp(-2*pi*i*f), f in revolutions (v_sin/cos_f32 native domain), f in [0,0.2]
__device__ __forceinline__ float2 wtw(float f) {
    return make_float2(__builtin_amdgcn_cosf(f), -__builtin_amdgcn_sinf(f));
}

__device__ __forceinline__ float2 cmul(float2 a, float2 b) {
    return make_float2(a.x * b.x - a.y * b.y, a.x * b.y + a.y * b.x);
}

// DIF butterfly: (a,b) -> (a+b, (a-b)*tw)
__device__ __forceinline__ void bfly(float2& a, float2& b, float2 tw) {
    float2 t = make_float2(a.x - b.x, a.y - b.y);
    a.x += b.x; a.y += b.y;
    b = cmul(t, tw);
}

// Four radix-2 DIF stages on 16 regs. v[m] holds virtual position base+stride*m
// of a length-L sub-FFT (stride = L/16); W1 = exp(-2*pi*i*base/L).
__device__ __forceinline__ void fft_block16(float2 v[16], float2 W1)
{
    // C16[m] = exp(-2*pi*i*m/16)
    constexpr float C16x[8] = {1.f,  0.92387953251128674f,  0.70710678118654757f,  0.38268343236508978f,
                               0.f, -0.38268343236508978f, -0.70710678118654757f, -0.92387953251128674f};
    constexpr float C16y[8] = {0.f, -0.38268343236508978f, -0.70710678118654757f, -0.92387953251128674f,
                              -1.f, -0.92387953251128674f, -0.70710678118654757f, -0.38268343236508978f};
    // C8[m] = exp(-2*pi*i*m/8)
    constexpr float C8x[4] = {1.f,  0.70710678118654757f,  0.f, -0.70710678118654757f};
    constexpr float C8y[4] = {0.f, -0.70710678118654757f, -1.f, -0.70710678118654757f};

    float2 W2 = cmul(W1, W1);
    float2 W4 = cmul(W2, W2);
    float2 W8 = cmul(W4, W4);

    #pragma unroll
    for (int m = 0; m < 8; ++m) {
        float2 tw = cmul(W1, make_float2(C16x[m], C16y[m]));
        bfly(v[m], v[m + 8], tw);
    }
    #pragma unroll
    for (int g = 0; g < 2; ++g) {
        #pragma unroll
        for (int m = 0; m < 4; ++m) {
            float2 tw = cmul(W2, make_float2(C8x[m], C8y[m]));
            bfly(v[8 * g + m], v[8 * g + m + 4], tw);
        }
    }
    float2 W4i = make_float2(W4.y, -W4.x);
    #pragma unroll
    for (int g = 0; g < 4; ++g) {
        bfly(v[4 * g + 0], v[4 * g + 2], W4);
        bfly(v[4 * g + 1], v[4 * g + 3], W4i);
    }
    #pragma unroll
    for (int g = 0; g < 8; ++g)
        bfly(v[2 * g], v[2 * g + 1], W8);
}

// One block per row. LDS: 32 KiB half2 + small fp32 scratch -> 4 blocks/CU.
// launch_bounds min-waves 4 (VGPR cap 128): r8's (512,8) forced a 32-VGPR cap
// and spilled v[16] to scratch (WRITE_SIZE 252 MB, 107 us). Do NOT tighten.
// r11 lesson: do NOT add per-block __threadfence (L2 writeback x1024, +25 us).
// Tail: plain device-scope atomicAdd of -snr/B into d_out (no fence, no flag,
// no second kernel); d_out zeroed by a 4-byte hipMemsetAsync node before us.
__global__ __launch_bounds__(THREADS, 4)
void negsnr_row_kernel(const float* __restrict__ x,
                       const float* __restrict__ targets,
                       float* __restrict__ out)
{
    __shared__ __half2 cf[MHALF];   // 32768 bytes: packed (re,im) fp16
    __shared__ float   red[12];     // wave partials [0..7], pulse at [8]
    const int row  = blockIdx.x;
    const int tid  = threadIdx.x;
    const int lane = tid & 63;
    const int wave = tid >> 6;

    // ---- Issue the 16 global loads FIRST (overlap latency with phase 0) ----
    const float2* xr = (const float2*)(x + (size_t)row * NREAL);
    float2 v[16];
    #pragma unroll
    for (int m = 0; m < 16; ++m) v[m] = xr[tid + 512 * m];

    // ---- Phase 0: ref_idx, analytic (4 candidates), exact fp32 replication ----
    const float step = 15.0f / 8192.0f;            // exact in fp32
    const float t_hz = targets[row] / 60.0f;       // fp32 divide, same as reference
    int ri;
    {
        int kf = (int)floorf(t_hz * (8192.0f / 15.0f));
        float best = 1e30f; ri = 0;
        #pragma unroll
        for (int d = -1; d <= 2; ++d) {            // ascending k, strict < => first-index ties
            int k = min(max(kf + d, 0), 8192);
            float dist = fabsf((float)k * step - t_hz);
            if (dist < best) { best = dist; ri = k; }
        }
    }

    // ---- Block 1: stages 0-3 (stride 512), regs -> LDS (fp16 pack) ----
    fft_block16(v, wtw((float)tid * (1.0f / 8192.0f)));
    #pragma unroll
    for (int m = 0; m < 16; ++m)
        cf[PHI(tid + 512 * m)] = __floats2half2_rn(v[m].x, v[m].y);
    __syncthreads();

    // ---- Block 2: stride 32 within 512-chunks, stages 4-7 ----
    const int low5 = tid & 31;
    const int base2 = low5 + ((tid >> 5) << 9);
    #pragma unroll
    for (int m = 0; m < 16; ++m) v[m] = __half22float2(cf[PHI(base2 + 32 * m)]);
    fft_block16(v, wtw((float)low5 * (1.0f / 512.0f)));
    #pragma unroll
    for (int m = 0; m < 16; ++m)
        cf[PHI(base2 + 32 * m)] = __floats2half2_rn(v[m].x, v[m].y);
    __syncthreads();

    // ---- Block 3: stride 2, stages 8-11 (base twiddle constant per parity) ----
    const int p = tid & 1;
    const int base3 = p + ((tid >> 1) << 5);
    #pragma unroll
    for (int m = 0; m < 16; ++m) v[m] = __half22float2(cf[PHI(base3 + 2 * m)]);
    {
        float2 U = p ? make_float2(0.98078528040323044f, -0.19509032201612825f)  // exp(-i*pi/16)
                     : make_float2(1.0f, 0.0f);
        fft_block16(v, U);
    }
    #pragma unroll
    for (int m = 0; m < 16; ++m)
        cf[PHI(base3 + 2 * m)] = __floats2half2_rn(v[m].x, v[m].y);
    __syncthreads();
    // LDS holds Y = FFT through stage 11. Stage 12 (tw=1) folded below:
    // even a: Z[a] = Y[a]+Y[a+1]; odd b: Z[b] = Y[b-1]-Y[b]; X[k] = Z[br13(k)].

    // ---- Phase 3: rfft untangle for k in [364,2276), P1, masked sum ----
    // Twiddle recurrence: tw(k+512) = tw(k) * wtw(512/16384 = 1/32).
    const float2 CSTEP = make_float2(0.98078528040323044f, -0.19509032201612825f);
    float2 tw = wtw((float)(MIN_IDX + tid) * (1.0f / 16384.0f));
    float other = 0.0f, pulse = 0.0f;
    bool hasp = false;
    for (int k = MIN_IDX + tid; k < MAX_IDX; k += THREADS) {
        int a = br13(k);              // even (k < 4096)
        int b = br13(MHALF - k);      // odd  (8192-k >= 4096)
        int sa = PHI(a);              // {Y[a],Y[a+1]} at aligned pair {sa&~1, sa|1}
        int sb = PHI(b - 1);          // {Y[b-1],Y[b]} at aligned pair, maybe swapped
        // b64 paired reads (adjacent aligned slots)
        float2 ua = *(const float2*)&cf[sa & ~1];
        float2 ub = *(const float2*)&cf[sb & ~1];
        __half2 ha0 = *(__half2*)&ua.x, ha1 = *(__half2*)&ua.y;
        __half2 hb0 = *(__half2*)&ub.x, hb1 = *(__half2*)&ub.y;
        float2 e0 = __half22float2(ha0), e1 = __half22float2(ha1);
        float2 f0 = __half22float2(hb0), f1 = __half22float2(hb1);
        // Z[k] = Y[a]+Y[a+1]: order-independent -> no swap needed.
        float Zr = e0.x + e1.x, Zi = e0.y + e1.y;
        // Z[8192-k] = Y[b-1]-Y[b] = sgn*(f0-f1), sgn = -1 iff sb odd.
        float sgn = (sb & 1) ? -1.0f : 1.0f;
        float Zmr = (f0.x - f1.x) * sgn, Zmi = (f0.y - f1.y) * sgn;
        // Xe = (Z + conj(Zm))/2 ; Xo = (Z - conj(Zm))/(2i); X = Xe + W_N^k * Xo
        float xer  = 0.5f * (Zr + Zmr), xei = 0.5f * (Zi - Zmi);
        float xor_ = 0.5f * (Zi + Zmi), xoi = -0.5f * (Zr - Zmr);
        float xr_ = xer + tw.x * xor_ - tw.y * xoi;
        float xi_ = xei + tw.x * xoi + tw.y * xor_;
        float pw = xr_ * xr_ + xi_ * xi_;
        if (k < ri - 1 || k > ri + 1) other += pw;     // mask: [364,ri-1) U [ri+2,2276)
        if (k == ri) { pulse = pw; hasp = true; }
        tw = cmul(tw, CSTEP);
    }
    if (hasp) red[8] = pulse;        // exactly one writer (ri in [409,1776])
    #pragma unroll
    for (int off = 32; off; off >>= 1) other += __shfl_down(other, off);
    if (lane == 0) red[wave] = other;
    __syncthreads();
    if (tid == 0) {
        float tot = 0.0f;
        #pragma unroll
        for (int w = 0; w < 8; ++w) tot += red[w];
        const float denom = (float)(MAX_IDX - MIN_IDX - 3);   // 1909
        float snr = 10.0f * log10f(red[8] * denom / tot);
        // Device-scope atomic (G12/m20: cheap, no fence needed). One per block.
        atomicAdd(out, snr * (-1.0f / (float)gridDim.x));
    }
}

extern "C" void kernel_launch(void* const* d_in, const int* in_sizes, int n_in,
                              void* d_out, int out_size, void* d_ws, size_t ws_size,
                              hipStream_t stream) {
    const float* outputs = (const float*)d_in[0];
    const float* targets = (const float*)d_in[1];
    const int B = in_sizes[1];                 // 1024 rows

    hipMemsetAsync(d_out, 0, sizeof(float), stream);   // graph-capturable node
    negsnr_row_kernel<<<B, THREADS, 0, stream>>>(outputs, targets, (float*)d_out);
}

// Round 15
// 30.885 us; speedup vs baseline: 1.1718x; 1.1718x over previous
//
#include <hip/hip_runtime.h>
#include <hip/hip_fp16.h>
#include <math.h>

#define THREADS 512
#define MHALF 8192      // complex FFT length (N/2)
#define NREAL 16384
#define MIN_IDX 364     // argmin |f - 40/60|, exact fp32 (f[k]=k*15/8192 is exact)
#define MAX_IDX 2276    // argmin |f - 250/60|, exact fp32

__device__ __forceinline__ int br13(int x) {
    return (int)(__brev((unsigned)x) >> 19);
}

// Element p (a half2 = one complex) lives at cf[PHI(p)], 4-byte granularity.
// PHI(p) = p ^ ((p>>5)&31) ^ ((p>>10)&3). Measured (r8/r9):
// SQ_LDS_BANK_CONFLICT 1.29e6 (10x below the old bit0-preserving swizzle).
// PHI(p^1) = PHI(p)^1 (bit0 of p doesn't feed the masks), so a natural pair
// {even a, a+1} occupies an aligned slot pair {s&~1, s|1}, possibly swapped.
__device__ __forceinline__ int PHI(int p) {
    return p ^ ((p >> 5) & 31) ^ ((p >> 10) & 3);
}

// exp(-2*pi*i*f), f in revolutions (v_sin/cos_f32 native domain), f in [0,0.2]
__device__ __forceinline__ float2 wtw(float f) {
    return make_float2(__builtin_amdgcn_cosf(f), -__builtin_amdgcn_sinf(f));
}

__device__ __forceinline__ float2 cmul(float2 a, float2 b) {
    return make_float2(a.x * b.x - a.y * b.y, a.x * b.y + a.y * b.x);
}

// DIF butterfly: (a,b) -> (a+b, (a-b)*tw)
__device__ __forceinline__ void bfly(float2& a, float2& b, float2 tw) {
    float2 t = make_float2(a.x - b.x, a.y - b.y);
    a.x += b.x; a.y += b.y;
    b = cmul(t, tw);
}

// Four radix-2 DIF stages on 16 regs. v[m] holds virtual position base+stride*m
// of a length-L sub-FFT (stride = L/16); W1 = exp(-2*pi*i*base/L).
__device__ __forceinline__ void fft_block16(float2 v[16], float2 W1)
{
    // C16[m] = exp(-2*pi*i*m/16)
    constexpr float C16x[8] = {1.f,  0.92387953251128674f,  0.70710678118654757f,  0.38268343236508978f,
                               0.f, -0.38268343236508978f, -0.70710678118654757f, -0.92387953251128674f};
    constexpr float C16y[8] = {0.f, -0.38268343236508978f, -0.70710678118654757f, -0.92387953251128674f,
                              -1.f, -0.92387953251128674f, -0.70710678118654757f, -0.38268343236508978f};
    // C8[m] = exp(-2*pi*i*m/8)
    constexpr float C8x[4] = {1.f,  0.70710678118654757f,  0.f, -0.70710678118654757f};
    constexpr float C8y[4] = {0.f, -0.70710678118654757f, -1.f, -0.70710678118654757f};

    float2 W2 = cmul(W1, W1);
    float2 W4 = cmul(W2, W2);
    float2 W8 = cmul(W4, W4);

    #pragma unroll
    for (int m = 0; m < 8; ++m) {
        float2 tw = cmul(W1, make_float2(C16x[m], C16y[m]));
        bfly(v[m], v[m + 8], tw);
    }
    #pragma unroll
    for (int g = 0; g < 2; ++g) {
        #pragma unroll
        for (int m = 0; m < 4; ++m) {
            float2 tw = cmul(W2, make_float2(C8x[m], C8y[m]));
            bfly(v[8 * g + m], v[8 * g + m + 4], tw);
        }
    }
    float2 W4i = make_float2(W4.y, -W4.x);
    #pragma unroll
    for (int g = 0; g < 4; ++g) {
        bfly(v[4 * g + 0], v[4 * g + 2], W4);
        bfly(v[4 * g + 1], v[4 * g + 3], W4i);
    }
    #pragma unroll
    for (int g = 0; g < 8; ++g)
        bfly(v[2 * g], v[2 * g + 1], W8);
}

// One block per row. LDS: 32 KiB half2 + small fp32 scratch -> 4 blocks/CU.
// launch_bounds min-waves 4 (VGPR cap 128): r8's (512,8) forced a 32-VGPR cap
// and spilled v[16] to scratch (WRITE_SIZE 252 MB, 107 us). Do NOT tighten.
// r11 lesson: per-block __threadfence tail = +25 us (1024 L2 writebacks).
// r14 lesson: single-address atomicAdd tail = +9 us (1024-way cross-XCD
// contention on one cacheline). The tiny second kernel is the fastest tail.
__global__ __launch_bounds__(THREADS, 4)
void negsnr_row_kernel(const float* __restrict__ x,
                       const float* __restrict__ targets,
                       float* __restrict__ snr_out)
{
    __shared__ __half2 cf[MHALF];   // 32768 bytes: packed (re,im) fp16
    __shared__ float   red[12];     // wave partials [0..7], pulse at [8]
    const int row  = blockIdx.x;
    const int tid  = threadIdx.x;
    const int lane = tid & 63;
    const int wave = tid >> 6;

    // ---- Issue the 16 global loads FIRST (overlap latency with phase 0) ----
    const float2* xr = (const float2*)(x + (size_t)row * NREAL);
    float2 v[16];
    #pragma unroll
    for (int m = 0; m < 16; ++m) v[m] = xr[tid + 512 * m];

    // ---- Phase 0: ref_idx, analytic (4 candidates), exact fp32 replication ----
    const float step = 15.0f / 8192.0f;            // exact in fp32
    const float t_hz = targets[row] / 60.0f;       // fp32 divide, same as reference
    int ri;
    {
        int kf = (int)floorf(t_hz * (8192.0f / 15.0f));
        float best = 1e30f; ri = 0;
        #pragma unroll
        for (int d = -1; d <= 2; ++d) {            // ascending k, strict < => first-index ties
            int k = min(max(kf + d, 0), 8192);
            float dist = fabsf((float)k * step - t_hz);
            if (dist < best) { best = dist; ri = k; }
        }
    }

    // ---- Block 1: stages 0-3 (stride 512), regs -> LDS (fp16 pack) ----
    fft_block16(v, wtw((float)tid * (1.0f / 8192.0f)));
    #pragma unroll
    for (int m = 0; m < 16; ++m)
        cf[PHI(tid + 512 * m)] = __floats2half2_rn(v[m].x, v[m].y);
    __syncthreads();

    // ---- Block 2: stride 32 within 512-chunks, stages 4-7 ----
    const int low5 = tid & 31;
    const int base2 = low5 + ((tid >> 5) << 9);
    #pragma unroll
    for (int m = 0; m < 16; ++m) v[m] = __half22float2(cf[PHI(base2 + 32 * m)]);
    fft_block16(v, wtw((float)low5 * (1.0f / 512.0f)));
    #pragma unroll
    for (int m = 0; m < 16; ++m)
        cf[PHI(base2 + 32 * m)] = __floats2half2_rn(v[m].x, v[m].y);
    __syncthreads();

    // ---- Block 3: stride 2, stages 8-11 (base twiddle constant per parity) ----
    const int p = tid & 1;
    const int base3 = p + ((tid >> 1) << 5);
    #pragma unroll
    for (int m = 0; m < 16; ++m) v[m] = __half22float2(cf[PHI(base3 + 2 * m)]);
    {
        float2 U = p ? make_float2(0.98078528040323044f, -0.19509032201612825f)  // exp(-i*pi/16)
                     : make_float2(1.0f, 0.0f);
        fft_block16(v, U);
    }
    #pragma unroll
    for (int m = 0; m < 16; ++m)
        cf[PHI(base3 + 2 * m)] = __floats2half2_rn(v[m].x, v[m].y);
    __syncthreads();
    // LDS holds Y = FFT through stage 11. Stage 12 (tw=1) folded below:
    // even a: Z[a] = Y[a]+Y[a+1]; odd b: Z[b] = Y[b-1]-Y[b]; X[k] = Z[br13(k)].

    // ---- Phase 3: rfft untangle for k in [364,2276), P1, masked sum ----
    // Twiddle recurrence: tw(k+512) = tw(k) * wtw(512/16384 = 1/32).
    const float2 CSTEP = make_float2(0.98078528040323044f, -0.19509032201612825f);
    float2 tw = wtw((float)(MIN_IDX + tid) * (1.0f / 16384.0f));
    float other = 0.0f, pulse = 0.0f;
    bool hasp = false;
    for (int k = MIN_IDX + tid; k < MAX_IDX; k += THREADS) {
        int a = br13(k);              // even (k < 4096)
        int b = br13(MHALF - k);      // odd  (8192-k >= 4096)
        int sa = PHI(a);              // {Y[a],Y[a+1]} at aligned pair {sa&~1, sa|1}
        int sb = PHI(b - 1);          // {Y[b-1],Y[b]} at aligned pair, maybe swapped
        // b64 paired reads (adjacent aligned slots)
        float2 ua = *(const float2*)&cf[sa & ~1];
        float2 ub = *(const float2*)&cf[sb & ~1];
        __half2 ha0 = *(__half2*)&ua.x, ha1 = *(__half2*)&ua.y;
        __half2 hb0 = *(__half2*)&ub.x, hb1 = *(__half2*)&ub.y;
        float2 e0 = __half22float2(ha0), e1 = __half22float2(ha1);
        float2 f0 = __half22float2(hb0), f1 = __half22float2(hb1);
        // Z[k] = Y[a]+Y[a+1]: order-independent -> no swap needed.
        float Zr = e0.x + e1.x, Zi = e0.y + e1.y;
        // Z[8192-k] = Y[b-1]-Y[b] = sgn*(f0-f1), sgn = -1 iff sb odd.
        float sgn = (sb & 1) ? -1.0f : 1.0f;
        float Zmr = (f0.x - f1.x) * sgn, Zmi = (f0.y - f1.y) * sgn;
        // Xe = (Z + conj(Zm))/2 ; Xo = (Z - conj(Zm))/(2i); X = Xe + W_N^k * Xo
        float xer  = 0.5f * (Zr + Zmr), xei = 0.5f * (Zi - Zmi);
        float xor_ = 0.5f * (Zi + Zmi), xoi = -0.5f * (Zr - Zmr);
        float xr_ = xer + tw.x * xor_ - tw.y * xoi;
        float xi_ = xei + tw.x * xoi + tw.y * xor_;
        float pw = xr_ * xr_ + xi_ * xi_;
        if (k < ri - 1 || k > ri + 1) other += pw;     // mask: [364,ri-1) U [ri+2,2276)
        if (k == ri) { pulse = pw; hasp = true; }
        tw = cmul(tw, CSTEP);
    }
    if (hasp) red[8] = pulse;        // exactly one writer (ri in [409,1776])
    #pragma unroll
    for (int off = 32; off; off >>= 1) other += __shfl_down(other, off);
    if (lane == 0) red[wave] = other;
    __syncthreads();
    if (tid == 0) {
        float tot = 0.0f;
        #pragma unroll
        for (int w = 0; w < 8; ++w) tot += red[w];
        const float denom = (float)(MAX_IDX - MIN_IDX - 3);   // 1909
        snr_out[row] = 10.0f * log10f(red[8] * denom / tot);
    }
}

__global__ void negsnr_mean_kernel(const float* __restrict__ snr,
                                   float* __restrict__ out, int n)
{
    __shared__ float sacc[8];
    const int tid = threadIdx.x;
    float acc = 0.0f;
    for (int i = tid; i < n; i += 512) acc += snr[i];
    #pragma unroll
    for (int off = 32; off; off >>= 1) acc += __shfl_down(acc, off);
    if ((tid & 63) == 0) sacc[tid >> 6] = acc;
    __syncthreads();
    if (tid == 0) {
        float t = 0.0f;
        #pragma unroll
        for (int w = 0; w < 8; ++w) t += sacc[w];
        out[0] = -t / (float)n;
    }
}

extern "C" void kernel_launch(void* const* d_in, const int* in_sizes, int n_in,
                              void* d_out, int out_size, void* d_ws, size_t ws_size,
                              hipStream_t stream) {
    const float* outputs = (const float*)d_in[0];
    const float* targets = (const float*)d_in[1];
    const int B = in_sizes[1];                 // 1024 rows
    float* snr = (float*)d_ws;                 // B floats of scratch

    negsnr_row_kernel<<<B, THREADS, 0, stream>>>(outputs, targets, snr);
    negsnr_mean_kernel<<<1, 512, 0, stream>>>(snr, (float*)d_out, B);
}